// Round 19
// baseline (190.677 us; speedup 1.0000x reference)
//
#include <hip/hip_runtime.h>
#include <hip/hip_bf16.h>

// TurboQuantMSE: x_hat = Q(x @ R^T) @ R, Q = 16-level Lloyd-Max quantizer.
// Round 19: R18's producer-consumer structure with 32x32x16 MFMA consumers.
// Same 64x64 wave tile now = 16 x mfma_f32_32x32x16_f16 (8.07cyc, 128cyc
// matrix time) instead of 32 x 16x16x32 (4.85cyc, 155cyc) — half the MFMA
// issue slots, 17% less matrix-pipe time, identical ds_read volume. A/B frag:
// row=lane&31, k=(lane>>5)*8+elem; C/D: col=lane&31,
// row=(reg&3)+8*(reg>>2)+4*(lane>>5) [m74/m101]. Producer/schedule = R18
// (counted vmcnt(12), 3x48KB buffers, 1 barrier/tile).

typedef __attribute__((ext_vector_type(8))) _Float16 f16x8;
typedef __attribute__((ext_vector_type(16))) float f32x16;

__device__ __forceinline__ unsigned short f2h(float f) {
    _Float16 h = (_Float16)f;
    return *reinterpret_cast<unsigned short*>(&h);
}

__device__ __forceinline__ float quant16(float yn, const float* c) {
    float v = c[0];
#pragma unroll
    for (int i = 0; i < 15; i++) {
        const float bnd = 0.5f * (c[i] + c[i + 1]);
        v = (yn > bnd) ? c[i + 1] : v;
    }
    return v;
}

// ---------------- elementwise f32 -> fp16 (x) ----------------
__global__ __launch_bounds__(256) void convert_x_kernel(
    const float* __restrict__ x, unsigned short* __restrict__ xb) {
    const int i = (blockIdx.x * 256 + threadIdx.x) * 4;
    float4 v = *reinterpret_cast<const float4*>(x + i);
    ushort4 b;
    b.x = f2h(v.x); b.y = f2h(v.y); b.z = f2h(v.z); b.w = f2h(v.w);
    *reinterpret_cast<ushort4*>(xb + i) = b;
}

// ---------------- rotation f32 -> fp16 (row-major) + fp16 transposed --------
__global__ __launch_bounds__(256) void conv_rot_kernel(
    const float* __restrict__ R, unsigned short* __restrict__ Rb,
    unsigned short* __restrict__ Rt) {
    __shared__ float t[64][65];
    const int tid = threadIdx.x;
    const int tr = blockIdx.y * 64, tc = blockIdx.x * 64;
    const int r0 = tid >> 4;
    const int c4 = (tid & 15) << 2;
#pragma unroll
    for (int i = 0; i < 4; i++) {
        const int r = r0 + i * 16;
        float4 v = *reinterpret_cast<const float4*>(
            &R[(size_t)(tr + r) * 4096 + tc + c4]);
        ushort4 b;
        b.x = f2h(v.x); b.y = f2h(v.y); b.z = f2h(v.z); b.w = f2h(v.w);
        *reinterpret_cast<ushort4*>(&Rb[(size_t)(tr + r) * 4096 + tc + c4]) = b;
        t[r][c4 + 0] = v.x; t[r][c4 + 1] = v.y;
        t[r][c4 + 2] = v.z; t[r][c4 + 3] = v.w;
    }
    __syncthreads();
#pragma unroll
    for (int i = 0; i < 16; i++) {
        const int idx = tid + 256 * i;
        const int rr = idx >> 6;
        const int cc = idx & 63;
        Rt[(size_t)(tc + rr) * 4096 + tr + cc] = f2h(t[cc][rr]);
    }
}

// ---------------- producer/consumer NT GEMM, 32x32 MFMA ----------------------
// C[2048,4096] = A[2048,K] * Bt[4096,K]^T, fp16 in, f32 accum.
// BM=128 BN=256 BK=64. Waves 0..7 consume (64x64, 2x2 32x32 frags);
// 8..11 produce. 3 LDS buffers x 48KB. One barrier/tile, no steady drains.
constexpr int GK = 4096;
constexpr int BM = 128, BN = 256, BK = 64;
constexpr int NT = GK / BK;                 // 64
constexpr int A_LDS = BM * BK * 2;          // 16384
constexpr int BUF = (BM + BN) * BK * 2;     // 49152
constexpr int LDS_DYN = 3 * BUF;            // 147456

template <bool QUANT>
__global__ __launch_bounds__(768, 3) void gemm_nt_kernel(
    const unsigned short* __restrict__ A, const unsigned short* __restrict__ Bt,
    void* __restrict__ Cout, const float* __restrict__ cb16) {
    extern __shared__ char smem[];
    const int tid = threadIdx.x;
    const int lane = tid & 63;
    const int w = tid >> 6;        // 0..11

    // XCD-aware bijective swizzle (256 blocks, 256%8==0)
    const int bid = blockIdx.x;
    const int wgid = (bid & 7) * 32 + (bid >> 3);
    const int tn = wgid & 15;      // N/BN = 16
    const int tm = wgid >> 4;      // M/BM = 16

    if (w >= 8) {
        // ================= PRODUCER (waves 8..11) =================
        const int tp = tid - 512;            // 0..255
        const int pw = tp >> 6;              // 0..3
        const int prow = tp >> 3;            // 0..31
        const int pcol = (((tp & 7) ^ (prow & 7)) << 3);  // pre-swizzled col
        const unsigned short* P[12];
#pragma unroll
        for (int r = 0; r < 12; r++) {
            const int rir = r * 32 + prow;   // row in 48KB region
            P[r] = (rir < BM)
                ? A + (size_t)(tm * BM + rir) * GK + pcol
                : Bt + (size_t)(tn * BN + (rir - BM)) * GK + pcol;
        }
#define PSTAGE(dstbase)                                                        \
        {                                                                      \
            _Pragma("unroll")                                                  \
            for (int r = 0; r < 12; r++) {                                     \
                __builtin_amdgcn_global_load_lds(                              \
                    (const __attribute__((address_space(1))) void*)P[r],       \
                    (__attribute__((address_space(3))) void*)(                 \
                        smem + (dstbase) + r * 4096 + pw * 1024), 16, 0, 0);   \
                P[r] += BK;                                                    \
            }                                                                  \
        }
        // prologue: stage tiles 0,1; tile 0 must be landed (24 -> 12)
        PSTAGE(0)
        PSTAGE(BUF)
        asm volatile("s_waitcnt vmcnt(12)" ::: "memory");
        __builtin_amdgcn_s_barrier();
        __builtin_amdgcn_sched_barrier(0);
        int wb = 2 * BUF;   // buffer receiving tile t+2
        for (int t = 0; t < NT; ++t) {
            if (t + 2 < NT) {
                PSTAGE(wb)
                asm volatile("s_waitcnt vmcnt(12)" ::: "memory");
            } else {
                asm volatile("s_waitcnt vmcnt(0)" ::: "memory");
            }
            __builtin_amdgcn_s_barrier();
            __builtin_amdgcn_sched_barrier(0);
            wb = (wb == 2 * BUF) ? 0 : wb + BUF;
        }
#undef PSTAGE
        return;
    }

    // ================= CONSUMER (waves 0..7) =================
    const int wm = w >> 2;         // 0..1
    const int wn = w & 3;          // 0..3
    const int row32 = lane & 31;   // frag row (A) / col (B/C)
    const int khalf = lane >> 5;   // 0..1 — k sub-half within a k-step

    f32x16 acc00 = {0}, acc01 = {0}, acc10 = {0}, acc11 = {0};

    // LDS byte addr: row*128 + ((slot) ^ (row&7))*16, slot = ks*2 + khalf
    const int arow0 = (wm * 64 + row32) * 128;            // A, m=0 (+32*128 for m=1)
    const int brow0 = A_LDS + (wn * 64 + row32) * 128;    // B, n=0
    const int swz = row32 & 7;

#define LDA(base, m, ks) (*reinterpret_cast<const f16x8*>( \
    smem + (base) + arow0 + (m) * 4096 + ((((ks) * 2 + khalf) ^ swz) << 4)))
#define LDB(base, n, ks) (*reinterpret_cast<const f16x8*>( \
    smem + (base) + brow0 + (n) * 4096 + ((((ks) * 2 + khalf) ^ swz) << 4)))
#define MFMA4(A0, A1, B0, B1)                                                      \
    acc00 = __builtin_amdgcn_mfma_f32_32x32x16_f16(A0, B0, acc00, 0, 0, 0);        \
    acc01 = __builtin_amdgcn_mfma_f32_32x32x16_f16(A0, B1, acc01, 0, 0, 0);        \
    acc10 = __builtin_amdgcn_mfma_f32_32x32x16_f16(A1, B0, acc10, 0, 0, 0);        \
    acc11 = __builtin_amdgcn_mfma_f32_32x32x16_f16(A1, B1, acc11, 0, 0, 0);

    // prologue: wait producers' tile-0 stage
    __builtin_amdgcn_s_barrier();
    __builtin_amdgcn_sched_barrier(0);

    int lb = 0;
    for (int t = 0; t < NT; ++t) {
        f16x8 a00, a01, b00, b01, a10, a11, b10, b11;   // ksteps 0,1
        f16x8 a20, a21, b20, b21, a30, a31, b30, b31;   // ksteps 2,3
        a00 = LDA(lb, 0, 0); a01 = LDA(lb, 1, 0);
        b00 = LDB(lb, 0, 0); b01 = LDB(lb, 1, 0);
        a10 = LDA(lb, 0, 1); a11 = LDA(lb, 1, 1);
        b10 = LDB(lb, 0, 1); b11 = LDB(lb, 1, 1);
        a20 = LDA(lb, 0, 2); a21 = LDA(lb, 1, 2);
        b20 = LDB(lb, 0, 2); b21 = LDB(lb, 1, 2);
        a30 = LDA(lb, 0, 3); a31 = LDA(lb, 1, 3);
        b30 = LDB(lb, 0, 3); b31 = LDB(lb, 1, 3);
        asm volatile("s_waitcnt lgkmcnt(8)" ::: "memory");
        __builtin_amdgcn_sched_barrier(0);
        __builtin_amdgcn_s_setprio(1);
        MFMA4(a00, a01, b00, b01)
        MFMA4(a10, a11, b10, b11)
        __builtin_amdgcn_s_setprio(0);
        asm volatile("s_waitcnt lgkmcnt(0)" ::: "memory");
        __builtin_amdgcn_sched_barrier(0);
        __builtin_amdgcn_s_setprio(1);
        MFMA4(a20, a21, b20, b21)
        MFMA4(a30, a31, b30, b31)
        __builtin_amdgcn_s_setprio(0);
        __builtin_amdgcn_s_barrier();
        __builtin_amdgcn_sched_barrier(0);
        lb = (lb == 2 * BUF) ? 0 : lb + BUF;
    }
#undef LDA
#undef LDB
#undef MFMA4

    // ---- epilogue: 32x32 C/D layout col=lane&31,
    //      row=(reg&3)+8*(reg>>2)+4*(lane>>5)  [m74/m101] ----
    const int erow0 = tm * BM + wm * 64 + 4 * khalf;
    const int ecol0 = tn * BN + wn * 64 + row32;
    if constexpr (QUANT) {
        float c[16];
#pragma unroll
        for (int i = 0; i < 16; i++) c[i] = cb16[i];
        unsigned short* O = (unsigned short*)Cout;
#define EPIQ(ACC, m, n)                                                        \
        _Pragma("unroll")                                                      \
        for (int r = 0; r < 16; r++) {                                         \
            const int rr = erow0 + (m) * 32 + (r & 3) + 8 * (r >> 2);          \
            O[(size_t)rr * 4096 + ecol0 + (n) * 32] =                          \
                f2h(quant16(ACC[r] * 64.0f, c) * 0.015625f);                   \
        }
        EPIQ(acc00, 0, 0) EPIQ(acc01, 0, 1) EPIQ(acc10, 1, 0) EPIQ(acc11, 1, 1)
#undef EPIQ
    } else {
        float* O = (float*)Cout;
#define EPIF(ACC, m, n)                                                        \
        _Pragma("unroll")                                                      \
        for (int r = 0; r < 16; r++) {                                         \
            const int rr = erow0 + (m) * 32 + (r & 3) + 8 * (r >> 2);          \
            O[(size_t)rr * 4096 + ecol0 + (n) * 32] = ACC[r];                  \
        }
        EPIF(acc00, 0, 0) EPIF(acc01, 0, 1) EPIF(acc10, 1, 0) EPIF(acc11, 1, 1)
#undef EPIF
    }
}

extern "C" void kernel_launch(void* const* d_in, const int* in_sizes, int n_in,
                              void* d_out, int out_size, void* d_ws,
                              size_t ws_size, hipStream_t stream) {
    const float* x = (const float*)d_in[0];
    const float* rot = (const float*)d_in[1];
    const float* cb = (const float*)d_in[2];
    float* out = (float*)d_out;

    unsigned short* Xh = (unsigned short*)d_ws;
    unsigned short* Rh = Xh + (size_t)2048 * 4096;
    unsigned short* Rt = Rh + (size_t)4096 * 4096;
    unsigned short* Yh = Rt + (size_t)4096 * 4096;

    (void)hipFuncSetAttribute(
        reinterpret_cast<const void*>(&gemm_nt_kernel<true>),
        hipFuncAttributeMaxDynamicSharedMemorySize, LDS_DYN);
    (void)hipFuncSetAttribute(
        reinterpret_cast<const void*>(&gemm_nt_kernel<false>),
        hipFuncAttributeMaxDynamicSharedMemorySize, LDS_DYN);

    convert_x_kernel<<<8192, 256, 0, stream>>>(x, Xh);
    conv_rot_kernel<<<dim3(64, 64), 256, 0, stream>>>(rot, Rh, Rt);
    // y = x @ R^T : NT GEMM, Bt = Rh
    gemm_nt_kernel<true><<<256, 768, LDS_DYN, stream>>>(Xh, Rh, (void*)Yh, cb);
    // x_hat = y_hat @ R = y_hat @ (R^T)^T : NT GEMM, Bt = Rt
    gemm_nt_kernel<false><<<256, 768, LDS_DYN, stream>>>(Yh, Rt, (void*)out, nullptr);
}

// Round 20
// 157.069 us; speedup vs baseline: 1.2140x; 1.2140x over previous
//
#include <hip/hip_runtime.h>
#include <hip/hip_bf16.h>

// TurboQuantMSE: x_hat = Q(x @ R^T) @ R, Q = 16-level Lloyd-Max quantizer.
// FINAL (restore of Round 18, the session best: 157.1us total, 73.7us/GEMM
// ~= 930 TF): producer-consumer wave specialization + counted-vmcnt producer.
// 12 waves: 8 consumers (64x64 over BM=128/BN=256, 16 ds_read + 32 MFMA per
// BK=64 tile, lgkm(8)/lgkm(0) mid-tile) + 4 producers (12 global_load_lds
// for tile t+2 into buf[(t+2)%3], vmcnt(12) so t+2's loads ride across the
// barrier). 3 LDS buffers x 48KB = 144KB. fp16 MFMA (fp16 needed: bf16's
// 2^-9 input rounding flips Lloyd-Max boundaries -> absmax 4.4e-3 > thr).
// R19's 32x32-MFMA variant regressed (unavoidable 4-way LDS slot aliasing,
// 8.4M bank conflicts); 16x16x32 + this swizzle is conflict-free (measured 0).

typedef __attribute__((ext_vector_type(8))) _Float16 f16x8;
typedef __attribute__((ext_vector_type(4))) float f32x4;

__device__ __forceinline__ unsigned short f2h(float f) {
    _Float16 h = (_Float16)f;
    return *reinterpret_cast<unsigned short*>(&h);
}

__device__ __forceinline__ float quant16(float yn, const float* c) {
    float v = c[0];
#pragma unroll
    for (int i = 0; i < 15; i++) {
        const float bnd = 0.5f * (c[i] + c[i + 1]);
        v = (yn > bnd) ? c[i + 1] : v;
    }
    return v;
}

// ---------------- elementwise f32 -> fp16 (x) ----------------
__global__ __launch_bounds__(256) void convert_x_kernel(
    const float* __restrict__ x, unsigned short* __restrict__ xb) {
    const int i = (blockIdx.x * 256 + threadIdx.x) * 4;
    float4 v = *reinterpret_cast<const float4*>(x + i);
    ushort4 b;
    b.x = f2h(v.x); b.y = f2h(v.y); b.z = f2h(v.z); b.w = f2h(v.w);
    *reinterpret_cast<ushort4*>(xb + i) = b;
}

// ---------------- rotation f32 -> fp16 (row-major) + fp16 transposed --------
__global__ __launch_bounds__(256) void conv_rot_kernel(
    const float* __restrict__ R, unsigned short* __restrict__ Rb,
    unsigned short* __restrict__ Rt) {
    __shared__ float t[64][65];
    const int tid = threadIdx.x;
    const int tr = blockIdx.y * 64, tc = blockIdx.x * 64;
    const int r0 = tid >> 4;
    const int c4 = (tid & 15) << 2;
#pragma unroll
    for (int i = 0; i < 4; i++) {
        const int r = r0 + i * 16;
        float4 v = *reinterpret_cast<const float4*>(
            &R[(size_t)(tr + r) * 4096 + tc + c4]);
        ushort4 b;
        b.x = f2h(v.x); b.y = f2h(v.y); b.z = f2h(v.z); b.w = f2h(v.w);
        *reinterpret_cast<ushort4*>(&Rb[(size_t)(tr + r) * 4096 + tc + c4]) = b;
        t[r][c4 + 0] = v.x; t[r][c4 + 1] = v.y;
        t[r][c4 + 2] = v.z; t[r][c4 + 3] = v.w;
    }
    __syncthreads();
#pragma unroll
    for (int i = 0; i < 16; i++) {
        const int idx = tid + 256 * i;
        const int rr = idx >> 6;
        const int cc = idx & 63;
        Rt[(size_t)(tc + rr) * 4096 + tr + cc] = f2h(t[cc][rr]);
    }
}

// ---------------- producer/consumer NT GEMM ----------------------------------
// C[2048,4096] = A[2048,K] * Bt[4096,K]^T, fp16 in, f32 accum.
// BM=128 BN=256 BK=64. Waves 0..7 consume (64x64, acc[4][4]); 8..11 produce.
// 3 LDS buffers x 48KB. One barrier/tile; no drains in steady state.
constexpr int GK = 4096;
constexpr int BM = 128, BN = 256, BK = 64;
constexpr int NT = GK / BK;                 // 64
constexpr int A_LDS = BM * BK * 2;          // 16384
constexpr int BUF = (BM + BN) * BK * 2;     // 49152
constexpr int LDS_DYN = 3 * BUF;            // 147456

template <bool QUANT>
__global__ __launch_bounds__(768, 3) void gemm_nt_kernel(
    const unsigned short* __restrict__ A, const unsigned short* __restrict__ Bt,
    void* __restrict__ Cout, const float* __restrict__ cb16) {
    extern __shared__ char smem[];
    const int tid = threadIdx.x;
    const int lane = tid & 63;
    const int w = tid >> 6;        // 0..11

    // XCD-aware bijective swizzle (256 blocks, 256%8==0)
    const int bid = blockIdx.x;
    const int wgid = (bid & 7) * 32 + (bid >> 3);
    const int tn = wgid & 15;      // N/BN = 16
    const int tm = wgid >> 4;      // M/BM = 16

    if (w >= 8) {
        // ================= PRODUCER (waves 8..11) =================
        const int tp = tid - 512;            // 0..255
        const int pw = tp >> 6;              // 0..3
        const int prow = tp >> 3;            // 0..31
        const int pcol = (((tp & 7) ^ (prow & 7)) << 3);  // pre-swizzled col
        const unsigned short* P[12];
#pragma unroll
        for (int r = 0; r < 12; r++) {
            const int rir = r * 32 + prow;   // row in 48KB region
            P[r] = (rir < BM)
                ? A + (size_t)(tm * BM + rir) * GK + pcol
                : Bt + (size_t)(tn * BN + (rir - BM)) * GK + pcol;
        }
#define PSTAGE(dstbase)                                                        \
        {                                                                      \
            _Pragma("unroll")                                                  \
            for (int r = 0; r < 12; r++) {                                     \
                __builtin_amdgcn_global_load_lds(                              \
                    (const __attribute__((address_space(1))) void*)P[r],       \
                    (__attribute__((address_space(3))) void*)(                 \
                        smem + (dstbase) + r * 4096 + pw * 1024), 16, 0, 0);   \
                P[r] += BK;                                                    \
            }                                                                  \
        }
        // prologue: stage tiles 0,1; tile 0 must be landed (24 -> 12)
        PSTAGE(0)
        PSTAGE(BUF)
        asm volatile("s_waitcnt vmcnt(12)" ::: "memory");
        __builtin_amdgcn_s_barrier();
        __builtin_amdgcn_sched_barrier(0);
        int wb = 2 * BUF;   // buffer receiving tile t+2
        for (int t = 0; t < NT; ++t) {
            if (t + 2 < NT) {
                PSTAGE(wb)
                // outstanding = {t+1:12, t+2:12} -> retire t+1; t+2 rides on
                asm volatile("s_waitcnt vmcnt(12)" ::: "memory");
            } else {
                // nothing new issued; retire everything (t+1 if present)
                asm volatile("s_waitcnt vmcnt(0)" ::: "memory");
            }
            __builtin_amdgcn_s_barrier();
            __builtin_amdgcn_sched_barrier(0);
            wb = (wb == 2 * BUF) ? 0 : wb + BUF;
        }
#undef PSTAGE
        return;
    }

    // ================= CONSUMER (waves 0..7) =================
    const int wm = w >> 2;         // 0..1
    const int wn = w & 3;          // 0..3

    f32x4 acc[4][4];
#pragma unroll
    for (int m = 0; m < 4; m++)
#pragma unroll
        for (int n = 0; n < 4; n++) acc[m][n] = (f32x4){0.f, 0.f, 0.f, 0.f};

    // fragment read addressing (swizzled): byte = row*128 + (kslot^row&7)*16
    const int frow = lane & 15;
    const int sw0 = (((lane >> 4) ^ (frow & 7)) << 4);        // kk=0
    const int sw1 = (((4 + (lane >> 4)) ^ (frow & 7)) << 4);  // kk=1
    const int arow = (wm * 64 + frow) * 128;
    const int brow = A_LDS + (wn * 64 + frow) * 128;

#define LDA(base, m, sw) (*reinterpret_cast<const f16x8*>(smem + (base) + arow + (m) * 2048 + (sw)))
#define LDB(base, n, sw) (*reinterpret_cast<const f16x8*>(smem + (base) + brow + (n) * 2048 + (sw)))
#define MFMA16(A0, A1, A2, A3, B0, B1, B2, B3)                                     \
    acc[0][0] = __builtin_amdgcn_mfma_f32_16x16x32_f16(A0, B0, acc[0][0], 0, 0, 0); \
    acc[0][1] = __builtin_amdgcn_mfma_f32_16x16x32_f16(A0, B1, acc[0][1], 0, 0, 0); \
    acc[0][2] = __builtin_amdgcn_mfma_f32_16x16x32_f16(A0, B2, acc[0][2], 0, 0, 0); \
    acc[0][3] = __builtin_amdgcn_mfma_f32_16x16x32_f16(A0, B3, acc[0][3], 0, 0, 0); \
    acc[1][0] = __builtin_amdgcn_mfma_f32_16x16x32_f16(A1, B0, acc[1][0], 0, 0, 0); \
    acc[1][1] = __builtin_amdgcn_mfma_f32_16x16x32_f16(A1, B1, acc[1][1], 0, 0, 0); \
    acc[1][2] = __builtin_amdgcn_mfma_f32_16x16x32_f16(A1, B2, acc[1][2], 0, 0, 0); \
    acc[1][3] = __builtin_amdgcn_mfma_f32_16x16x32_f16(A1, B3, acc[1][3], 0, 0, 0); \
    acc[2][0] = __builtin_amdgcn_mfma_f32_16x16x32_f16(A2, B0, acc[2][0], 0, 0, 0); \
    acc[2][1] = __builtin_amdgcn_mfma_f32_16x16x32_f16(A2, B1, acc[2][1], 0, 0, 0); \
    acc[2][2] = __builtin_amdgcn_mfma_f32_16x16x32_f16(A2, B2, acc[2][2], 0, 0, 0); \
    acc[2][3] = __builtin_amdgcn_mfma_f32_16x16x32_f16(A2, B3, acc[2][3], 0, 0, 0); \
    acc[3][0] = __builtin_amdgcn_mfma_f32_16x16x32_f16(A3, B0, acc[3][0], 0, 0, 0); \
    acc[3][1] = __builtin_amdgcn_mfma_f32_16x16x32_f16(A3, B1, acc[3][1], 0, 0, 0); \
    acc[3][2] = __builtin_amdgcn_mfma_f32_16x16x32_f16(A3, B2, acc[3][2], 0, 0, 0); \
    acc[3][3] = __builtin_amdgcn_mfma_f32_16x16x32_f16(A3, B3, acc[3][3], 0, 0, 0);

    // prologue: wait producers' tile-0 stage
    __builtin_amdgcn_s_barrier();
    __builtin_amdgcn_sched_barrier(0);

    int lb = 0;
    for (int t = 0; t < NT; ++t) {
        f16x8 a00, a01, a02, a03, b00, b01, b02, b03;
        f16x8 a10, a11, a12, a13, b10, b11, b12, b13;
        a00 = LDA(lb, 0, sw0); a01 = LDA(lb, 1, sw0); a02 = LDA(lb, 2, sw0); a03 = LDA(lb, 3, sw0);
        b00 = LDB(lb, 0, sw0); b01 = LDB(lb, 1, sw0); b02 = LDB(lb, 2, sw0); b03 = LDB(lb, 3, sw0);
        a10 = LDA(lb, 0, sw1); a11 = LDA(lb, 1, sw1); a12 = LDA(lb, 2, sw1); a13 = LDA(lb, 3, sw1);
        b10 = LDB(lb, 0, sw1); b11 = LDB(lb, 1, sw1); b12 = LDB(lb, 2, sw1); b13 = LDB(lb, 3, sw1);
        asm volatile("s_waitcnt lgkmcnt(8)" ::: "memory");
        __builtin_amdgcn_sched_barrier(0);
        __builtin_amdgcn_s_setprio(1);
        MFMA16(a00, a01, a02, a03, b00, b01, b02, b03)
        __builtin_amdgcn_s_setprio(0);
        asm volatile("s_waitcnt lgkmcnt(0)" ::: "memory");
        __builtin_amdgcn_sched_barrier(0);
        __builtin_amdgcn_s_setprio(1);
        MFMA16(a10, a11, a12, a13, b10, b11, b12, b13)
        __builtin_amdgcn_s_setprio(0);
        __builtin_amdgcn_s_barrier();
        __builtin_amdgcn_sched_barrier(0);
        lb = (lb == 2 * BUF) ? 0 : lb + BUF;
    }
#undef LDA
#undef LDB
#undef MFMA16

    // ---- epilogue: C/D layout col=lane&15, row=(lane>>4)*4+j ----
    const int crow0 = tm * BM + wm * 64 + ((lane >> 4) << 2);
    const int ccol0 = tn * BN + wn * 64 + frow;
    if constexpr (QUANT) {
        float c[16];
#pragma unroll
        for (int i = 0; i < 16; i++) c[i] = cb16[i];
        unsigned short* O = (unsigned short*)Cout;
#pragma unroll
        for (int m = 0; m < 4; m++)
#pragma unroll
            for (int n = 0; n < 4; n++)
#pragma unroll
                for (int j = 0; j < 4; j++)
                    O[(size_t)(crow0 + m * 16 + j) * 4096 + ccol0 + n * 16] =
                        f2h(quant16(acc[m][n][j] * 64.0f, c) * 0.015625f);
    } else {
        float* O = (float*)Cout;
#pragma unroll
        for (int m = 0; m < 4; m++)
#pragma unroll
            for (int n = 0; n < 4; n++)
#pragma unroll
                for (int j = 0; j < 4; j++)
                    O[(size_t)(crow0 + m * 16 + j) * 4096 + ccol0 + n * 16] =
                        acc[m][n][j];
    }
}

extern "C" void kernel_launch(void* const* d_in, const int* in_sizes, int n_in,
                              void* d_out, int out_size, void* d_ws,
                              size_t ws_size, hipStream_t stream) {
    const float* x = (const float*)d_in[0];
    const float* rot = (const float*)d_in[1];
    const float* cb = (const float*)d_in[2];
    float* out = (float*)d_out;

    unsigned short* Xh = (unsigned short*)d_ws;
    unsigned short* Rh = Xh + (size_t)2048 * 4096;
    unsigned short* Rt = Rh + (size_t)4096 * 4096;
    unsigned short* Yh = Rt + (size_t)4096 * 4096;

    (void)hipFuncSetAttribute(
        reinterpret_cast<const void*>(&gemm_nt_kernel<true>),
        hipFuncAttributeMaxDynamicSharedMemorySize, LDS_DYN);
    (void)hipFuncSetAttribute(
        reinterpret_cast<const void*>(&gemm_nt_kernel<false>),
        hipFuncAttributeMaxDynamicSharedMemorySize, LDS_DYN);

    convert_x_kernel<<<8192, 256, 0, stream>>>(x, Xh);
    conv_rot_kernel<<<dim3(64, 64), 256, 0, stream>>>(rot, Rh, Rt);
    // y = x @ R^T : NT GEMM, Bt = Rh
    gemm_nt_kernel<true><<<256, 768, LDS_DYN, stream>>>(Xh, Rh, (void*)Yh, cb);
    // x_hat = y_hat @ R = y_hat @ (R^T)^T : NT GEMM, Bt = Rt
    gemm_nt_kernel<false><<<256, 768, LDS_DYN, stream>>>(Yh, Rt, (void*)out, nullptr);
}